// Round 10
// baseline (317.926 us; speedup 1.0000x reference)
//
#include <hip/hip_runtime.h>
#include <cstdint>
#include <cstddef>

// ---------------------------------------------------------------------------
// GCN encoder: z = GCN3( relu(GCN2( relu(GCN1( LN(x) )) )) )
// R10: (1) double-buffered GEMM K-loop (1 barrier/iter, global loads
//      overlapped with MFMA); (2) CSR build uses packed 4B records
//      (dst<<16|src, valid since N<65536) and sort_bucket re-reads binned
//      from L2 instead of caching in LDS (35 KB LDS -> 4 blocks/CU).
//      Agg kernels unchanged from R7/R9 (L2 random-sector service floor).
// ---------------------------------------------------------------------------

typedef __attribute__((ext_vector_type(8))) __bf16 bf16x8;
typedef __attribute__((ext_vector_type(4))) float f32x4;
typedef _Float16 half_t;
typedef __attribute__((ext_vector_type(8))) _Float16 half8_t;

// ---------------- prep: zero ctl | wsplit x3 | ln_stats, by block range ----
__global__ __launch_bounds__(256) void prep_misc(
    const float* __restrict__ x, const float* __restrict__ W1,
    const float* __restrict__ W2, const float* __restrict__ W3,
    int* __restrict__ bcnt, int* __restrict__ bcur_zero,
    unsigned short* __restrict__ W1t_hi, unsigned short* __restrict__ W1t_lo,
    unsigned short* __restrict__ W2t_hi, unsigned short* __restrict__ W2t_lo,
    unsigned short* __restrict__ W3t_hi, unsigned short* __restrict__ W3t_lo,
    float* __restrict__ mu, float* __restrict__ rs, int n) {
  int blk = blockIdx.x;
  int tid = threadIdx.x;
  if (blk == 0) {
    bcnt[tid] = 0;
    bcur_zero[tid] = 0;
    return;
  }
  if (blk <= 224) {
    int idx = (blk - 1) * 256 + tid;
    const float* W;
    unsigned short *Th, *Tl;
    int K, NOUT;
    if (idx < 32768) {
      W = W1; Th = W1t_hi; Tl = W1t_lo; K = 256; NOUT = 128;
    } else if (idx < 49152) {
      idx -= 32768;
      W = W2; Th = W2t_hi; Tl = W2t_lo; K = 128; NOUT = 128;
    } else {
      idx -= 49152;
      W = W3; Th = W3t_hi; Tl = W3t_lo; K = 128; NOUT = 64;
    }
    int k = idx / NOUT, c = idx % NOUT;
    float v = W[idx];
    __bf16 h = (__bf16)v;
    __bf16 l = (__bf16)(v - (float)h);
    Th[(size_t)c * K + k] = __builtin_bit_cast(unsigned short, h);
    Tl[(size_t)c * K + k] = __builtin_bit_cast(unsigned short, l);
    return;
  }
  int wv = (blk - 225) * 4 + (tid >> 6);
  int lane = tid & 63;
  if (wv >= n) return;
  const float4* row = (const float4*)(x + (size_t)wv * 256);
  float4 v = row[lane];
  float s = v.x + v.y + v.z + v.w;
  float s2 = v.x * v.x + v.y * v.y + v.z * v.z + v.w * v.w;
  for (int off = 32; off > 0; off >>= 1) {
    s += __shfl_down(s, off);
    s2 += __shfl_down(s2, off);
  }
  if (lane == 0) {
    float m = s * (1.0f / 256.0f);
    float var = s2 * (1.0f / 256.0f) - m * m;
    mu[wv] = m;
    rs[wv] = rsqrtf(var + 1e-5f);
  }
}

// ---------------- CSR build: bucket sort by dst (packed 4B records) --------
__global__ __launch_bounds__(256) void hist_bucket(const int* __restrict__ dst,
                                                   int* __restrict__ bcnt, int E, int NB) {
  __shared__ int h[256];
  int t = threadIdx.x;
  h[t] = 0;
  __syncthreads();
  for (int e = blockIdx.x * 256 + t; e < E; e += gridDim.x * 256)
    atomicAdd(&h[dst[e] >> 8], 1);
  __syncthreads();
  if (t < NB && h[t]) atomicAdd(&bcnt[t], h[t]);
}

__global__ __launch_bounds__(256) void scan_buckets(const int* __restrict__ bcnt,
                                                    int* __restrict__ bbase,
                                                    int* __restrict__ bcur, int NB, int E) {
  __shared__ int tmp[256];
  int t = threadIdx.x;
  int v = (t < NB) ? bcnt[t] : 0;
  tmp[t] = v;
  __syncthreads();
  for (int off = 1; off < 256; off <<= 1) {
    int x = (t >= off) ? tmp[t - off] : 0;
    __syncthreads();
    tmp[t] += x;
    __syncthreads();
  }
  int excl = tmp[t] - v;
  if (t < NB) { bbase[t] = excl; bcur[t] = excl; }
  if (t == 0) bbase[NB] = E;
}

#define CHUNK 4096
// record = (dst << 16) | src  (both < 65536)
__global__ __launch_bounds__(256) void scatter_bins(const int* __restrict__ src,
                                                    const int* __restrict__ dst,
                                                    int* __restrict__ bcur,
                                                    unsigned int* __restrict__ binned, int E) {
  __shared__ unsigned int recs[CHUNK];  // 16 KB
  __shared__ int hist[256], lbase[256], resv[256], cur[256];
  int t = threadIdx.x;
  int e0 = blockIdx.x * CHUNK;
  if (e0 >= E) return;
  int len = min(CHUNK, E - e0);
  hist[t] = 0;
  cur[t] = 0;
  __syncthreads();
  for (int i = t; i < len; i += 256) atomicAdd(&hist[dst[e0 + i] >> 8], 1);
  __syncthreads();
  int v = hist[t];
  lbase[t] = v;
  __syncthreads();
  for (int off = 1; off < 256; off <<= 1) {
    int x = (t >= off) ? lbase[t - off] : 0;
    __syncthreads();
    lbase[t] += x;
    __syncthreads();
  }
  int myexcl = lbase[t] - v;
  if (v) resv[t] = atomicAdd(&bcur[t], v);
  __syncthreads();
  lbase[t] = myexcl;
  __syncthreads();
  for (int i = t; i < len; i += 256) {
    int d = dst[e0 + i], s = src[e0 + i];
    int b = d >> 8;
    int r = atomicAdd(&cur[b], 1);
    recs[lbase[b] + r] = ((unsigned int)d << 16) | (unsigned int)s;
  }
  __syncthreads();
  for (int i = t; i < len; i += 256) {
    unsigned int rc = recs[i];
    int b = rc >> 24;
    binned[resv[b] + (i - lbase[b])] = rc;
  }
}

#define MAXB 8192
// counting-sort one 256-node bucket; binned re-read from L2 (no record LDS)
__global__ __launch_bounds__(256) void sort_bucket(const unsigned int* __restrict__ binned,
                                                   const int* __restrict__ bbase,
                                                   int* __restrict__ srcs,
                                                   int* __restrict__ offs,
                                                   float* __restrict__ dinv,
                                                   int N, int NB, int E) {
  __shared__ int sstage[MAXB];  // 32 KB
  __shared__ int hist[256], nbase[256], cur[256], tmp[256];
  int b = blockIdx.x, t = threadIdx.x;
  int base = bbase[b], end = bbase[b + 1];
  int L = end - base;
  if (L > MAXB) L = MAXB;
  hist[t] = 0;
  __syncthreads();
  for (int i = t; i < L; i += 256)
    atomicAdd(&hist[(binned[base + i] >> 16) & 255], 1);
  __syncthreads();
  int v = hist[t];
  tmp[t] = v;
  __syncthreads();
  for (int off = 1; off < 256; off <<= 1) {
    int x = (t >= off) ? tmp[t - off] : 0;
    __syncthreads();
    tmp[t] += x;
    __syncthreads();
  }
  int excl = tmp[t] - v;
  nbase[t] = excl;
  cur[t] = excl;
  int node = (b << 8) + t;
  if (node < N) {
    offs[node] = base + excl;
    dinv[node] = rsqrtf(1.0f + (float)v);
  }
  if (b == NB - 1 && t == 0) offs[N] = E;
  __syncthreads();
  for (int i = t; i < L; i += 256) {
    unsigned int p = binned[base + i];
    int ld = (p >> 16) & 255;
    int slot = atomicAdd(&cur[ld], 1);
    sstage[slot] = (int)(p & 0xFFFFu);
  }
  __syncthreads();
  for (int i = t; i < L; i += 256) srcs[base + i] = sstage[i];
}

__global__ void fill_w(const int* __restrict__ srcs, const float* __restrict__ dinv,
                       int2* __restrict__ edges, int E) {
  int e = blockIdx.x * 256 + threadIdx.x;
  if (e < E) {
    int s = srcs[e];
    edges[e] = make_int2(s, __float_as_int(dinv[s]));
  }
}

// ---------------- double-buffered bf16x3 MFMA GEMM ----------------
template <int K, int NOUT, bool LN, bool A_FP16>
__launch_bounds__(256)
__global__ void gemm_mfma(const void* __restrict__ Avoid,
                          const unsigned short* __restrict__ Wt_hi,
                          const unsigned short* __restrict__ Wt_lo,
                          const float* __restrict__ mu, const float* __restrict__ rs,
                          const float* __restrict__ gamma, const float* __restrict__ beta,
                          half_t* __restrict__ out, int nrows) {
  constexpr int BM = 64, BK = 32;
  constexpr int NT = NOUT / 16;
  constexpr int T = K / BK;
  constexpr int NBI = NOUT / 64;
  __shared__ unsigned short As_hi[2][BM][BK];
  __shared__ unsigned short As_lo[2][BM][BK];
  __shared__ unsigned short Bs_hi[2][NOUT][BK];
  __shared__ unsigned short Bs_lo[2][NOUT][BK];

  const int tid = threadIdx.x;
  const int lane = tid & 63;
  const int w = tid >> 6;
  const int quad = lane >> 4;
  const int l16 = lane & 15;
  const int row0 = blockIdx.x * BM;

  // staging register state
  float4 a0, a1, gv, bv;
  half8_t av;
  uint4 bhr[NBI], blr[NBI];
  // A geometry
  const int rA0 = tid >> 3, c4 = (tid & 7) * 4;          // fp32 path (2 rows)
  const int rA = tid >> 2, c8a = (tid & 3) * 8;          // fp16 path (1 row)
  const int nB = tid >> 2, c8 = (tid & 3) * 8;           // B path
  int g0 = row0 + rA0; if (g0 > nrows - 1) g0 = nrows - 1;
  int g1 = row0 + 32 + rA0; if (g1 > nrows - 1) g1 = nrows - 1;
  int gA = row0 + rA; if (gA > nrows - 1) gA = nrows - 1;
  float m0 = 0.f, s0 = 0.f, m1 = 0.f, s1 = 0.f;
  if (LN && !A_FP16) { m0 = mu[g0]; s0 = rs[g0]; m1 = mu[g1]; s1 = rs[g1]; }

  auto load_tile = [&](int k0) {
    if (!A_FP16) {
      const float* A = (const float*)Avoid;
      a0 = *(const float4*)&A[(size_t)g0 * K + k0 + c4];
      a1 = *(const float4*)&A[(size_t)g1 * K + k0 + c4];
      if (LN) {
        gv = *(const float4*)&gamma[k0 + c4];
        bv = *(const float4*)&beta[k0 + c4];
      }
    } else {
      const half_t* A = (const half_t*)Avoid;
      av = *(const half8_t*)&A[(size_t)gA * K + k0 + c8a];
    }
#pragma unroll
    for (int i = 0; i < NBI; ++i) {
      int n = i * 64 + nB;
      bhr[i] = *(const uint4*)&Wt_hi[(size_t)n * K + k0 + c8];
      blr[i] = *(const uint4*)&Wt_lo[(size_t)n * K + k0 + c8];
    }
  };
  auto store_tile = [&](int buf) {
    if (!A_FP16) {
      float v0[4] = {a0.x, a0.y, a0.z, a0.w};
      float v1[4] = {a1.x, a1.y, a1.z, a1.w};
      if (LN) {
        float g4[4] = {gv.x, gv.y, gv.z, gv.w};
        float b4[4] = {bv.x, bv.y, bv.z, bv.w};
#pragma unroll
        for (int j = 0; j < 4; ++j) {
          v0[j] = (v0[j] - m0) * s0 * g4[j] + b4[j];
          v1[j] = (v1[j] - m1) * s1 * g4[j] + b4[j];
        }
      }
#pragma unroll
      for (int j = 0; j < 4; ++j) {
        __bf16 h0 = (__bf16)v0[j];
        As_hi[buf][rA0][c4 + j] = __builtin_bit_cast(unsigned short, h0);
        __bf16 l0 = (__bf16)(v0[j] - (float)h0);
        As_lo[buf][rA0][c4 + j] = __builtin_bit_cast(unsigned short, l0);
        __bf16 h1 = (__bf16)v1[j];
        As_hi[buf][32 + rA0][c4 + j] = __builtin_bit_cast(unsigned short, h1);
        __bf16 l1 = (__bf16)(v1[j] - (float)h1);
        As_lo[buf][32 + rA0][c4 + j] = __builtin_bit_cast(unsigned short, l1);
      }
    } else {
#pragma unroll
      for (int j = 0; j < 8; ++j) {
        float f = (float)av[j];
        __bf16 h = (__bf16)f;
        __bf16 l = (__bf16)(f - (float)h);
        As_hi[buf][rA][c8a + j] = __builtin_bit_cast(unsigned short, h);
        As_lo[buf][rA][c8a + j] = __builtin_bit_cast(unsigned short, l);
      }
    }
#pragma unroll
    for (int i = 0; i < NBI; ++i) {
      int n = i * 64 + nB;
      *(uint4*)&Bs_hi[buf][n][c8] = bhr[i];
      *(uint4*)&Bs_lo[buf][n][c8] = blr[i];
    }
  };

  f32x4 acc[NT];
#pragma unroll
  for (int t = 0; t < NT; ++t) acc[t] = (f32x4){0.f, 0.f, 0.f, 0.f};

  load_tile(0);
  store_tile(0);
  __syncthreads();
  for (int it = 0; it < T; ++it) {
    const int cur = it & 1;
    if (it + 1 < T) load_tile((it + 1) * BK);
    bf16x8 ah = *(const bf16x8*)&As_hi[cur][w * 16 + l16][quad * 8];
    bf16x8 al = *(const bf16x8*)&As_lo[cur][w * 16 + l16][quad * 8];
#pragma unroll
    for (int t = 0; t < NT; ++t) {
      bf16x8 bh = *(const bf16x8*)&Bs_hi[cur][t * 16 + l16][quad * 8];
      bf16x8 bl = *(const bf16x8*)&Bs_lo[cur][t * 16 + l16][quad * 8];
      acc[t] = __builtin_amdgcn_mfma_f32_16x16x32_bf16(ah, bh, acc[t], 0, 0, 0);
      acc[t] = __builtin_amdgcn_mfma_f32_16x16x32_bf16(al, bh, acc[t], 0, 0, 0);
      acc[t] = __builtin_amdgcn_mfma_f32_16x16x32_bf16(ah, bl, acc[t], 0, 0, 0);
    }
    if (it + 1 < T) {
      store_tile(1 - cur);
      __syncthreads();
    }
  }

#pragma unroll
  for (int t = 0; t < NT; ++t) {
#pragma unroll
    for (int r = 0; r < 4; ++r) {
      int grow = row0 + w * 16 + quad * 4 + r;
      if (grow < nrows) out[(size_t)grow * NOUT + t * 16 + l16] = (half_t)acc[t][r];
    }
  }
}

// ---------------- aggregation: quarter-wave gathers (R7) ----------------
__global__ __launch_bounds__(256) void agg128_h(const half_t* __restrict__ t,
                                                const int* __restrict__ offs,
                                                const int2* __restrict__ edges,
                                                const float* __restrict__ dinv,
                                                const float* __restrict__ bias,
                                                half_t* __restrict__ out, int n) {
  int gid = blockIdx.x * blockDim.x + threadIdx.x;
  int node = gid >> 6, lane = gid & 63;
  if (node >= n) return;
  int qw = lane >> 4;
  int fl = lane & 15;
  int e0 = offs[node], e1 = offs[node + 1];
  float acc[8] = {0.f, 0.f, 0.f, 0.f, 0.f, 0.f, 0.f, 0.f};
  int e = e0 + qw;
  for (; e + 12 < e1; e += 16) {
    int2 da = edges[e], db = edges[e + 4], dc = edges[e + 8], dd = edges[e + 12];
    half8_t va = *(const half8_t*)(t + ((size_t)da.x << 7) + fl * 8);
    half8_t vb = *(const half8_t*)(t + ((size_t)db.x << 7) + fl * 8);
    half8_t vc = *(const half8_t*)(t + ((size_t)dc.x << 7) + fl * 8);
    half8_t vd = *(const half8_t*)(t + ((size_t)dd.x << 7) + fl * 8);
    float wa = __int_as_float(da.y), wb = __int_as_float(db.y);
    float wc = __int_as_float(dc.y), wd = __int_as_float(dd.y);
#pragma unroll
    for (int j = 0; j < 8; ++j) {
      acc[j] = fmaf(wa, (float)va[j], acc[j]);
      acc[j] = fmaf(wb, (float)vb[j], acc[j]);
      acc[j] = fmaf(wc, (float)vc[j], acc[j]);
      acc[j] = fmaf(wd, (float)vd[j], acc[j]);
    }
  }
  for (; e < e1; e += 4) {
    int2 d = edges[e];
    half8_t v = *(const half8_t*)(t + ((size_t)d.x << 7) + fl * 8);
    float w = __int_as_float(d.y);
#pragma unroll
    for (int j = 0; j < 8; ++j) acc[j] = fmaf(w, (float)v[j], acc[j]);
  }
#pragma unroll
  for (int j = 0; j < 8; ++j) {
    acc[j] += __shfl_xor(acc[j], 16);
    acc[j] += __shfl_xor(acc[j], 32);
  }
  if (qw == 0) {
    float di = dinv[node];
    float dii = di * di;
    half8_t sv = *(const half8_t*)(t + ((size_t)node << 7) + fl * 8);
    float4 b0 = *(const float4*)(bias + fl * 8);
    float4 b1 = *(const float4*)(bias + fl * 8 + 4);
    float bb[8] = {b0.x, b0.y, b0.z, b0.w, b1.x, b1.y, b1.z, b1.w};
    half8_t o;
#pragma unroll
    for (int j = 0; j < 8; ++j) {
      float v = di * acc[j] + dii * (float)sv[j] + bb[j];
      o[j] = (half_t)fmaxf(v, 0.f);
    }
    *(half8_t*)(out + ((size_t)node << 7) + fl * 8) = o;
  }
}

__global__ __launch_bounds__(256) void agg64_h(const half_t* __restrict__ t,
                                               const int* __restrict__ offs,
                                               const int2* __restrict__ edges,
                                               const float* __restrict__ dinv,
                                               const float* __restrict__ bias,
                                               float* __restrict__ out, int n) {
  int gid = blockIdx.x * blockDim.x + threadIdx.x;
  int node = gid >> 6, lane = gid & 63;
  if (node >= n) return;
  int og = lane >> 3;
  int fl = lane & 7;
  int e0 = offs[node], e1 = offs[node + 1];
  float acc[8] = {0.f, 0.f, 0.f, 0.f, 0.f, 0.f, 0.f, 0.f};
  int e = e0 + og;
  for (; e + 8 < e1; e += 16) {
    int2 da = edges[e], db = edges[e + 8];
    half8_t va = *(const half8_t*)(t + ((size_t)da.x << 6) + fl * 8);
    half8_t vb = *(const half8_t*)(t + ((size_t)db.x << 6) + fl * 8);
    float wa = __int_as_float(da.y), wb = __int_as_float(db.y);
#pragma unroll
    for (int j = 0; j < 8; ++j) {
      acc[j] = fmaf(wa, (float)va[j], acc[j]);
      acc[j] = fmaf(wb, (float)vb[j], acc[j]);
    }
  }
  for (; e < e1; e += 8) {
    int2 d = edges[e];
    half8_t v = *(const half8_t*)(t + ((size_t)d.x << 6) + fl * 8);
    float w = __int_as_float(d.y);
#pragma unroll
    for (int j = 0; j < 8; ++j) acc[j] = fmaf(w, (float)v[j], acc[j]);
  }
#pragma unroll
  for (int j = 0; j < 8; ++j) {
    acc[j] += __shfl_xor(acc[j], 8);
    acc[j] += __shfl_xor(acc[j], 16);
    acc[j] += __shfl_xor(acc[j], 32);
  }
  if (og == 0) {
    float di = dinv[node];
    float dii = di * di;
    half8_t sv = *(const half8_t*)(t + ((size_t)node << 6) + fl * 8);
    float4 b0 = *(const float4*)(bias + fl * 8);
    float4 b1 = *(const float4*)(bias + fl * 8 + 4);
    float bb[8] = {b0.x, b0.y, b0.z, b0.w, b1.x, b1.y, b1.z, b1.w};
    float ov[8];
#pragma unroll
    for (int j = 0; j < 8; ++j) ov[j] = di * acc[j] + dii * (float)sv[j] + bb[j];
    *(float4*)(out + ((size_t)node << 6) + fl * 8) = make_float4(ov[0], ov[1], ov[2], ov[3]);
    *(float4*)(out + ((size_t)node << 6) + fl * 8 + 4) = make_float4(ov[4], ov[5], ov[6], ov[7]);
  }
}

extern "C" void kernel_launch(void* const* d_in, const int* in_sizes, int n_in,
                              void* d_out, int out_size, void* d_ws, size_t ws_size,
                              hipStream_t stream) {
  const float* x = (const float*)d_in[0];
  const int* ei = (const int*)d_in[1];
  const float* gamma = (const float*)d_in[2];
  const float* beta = (const float*)d_in[3];
  const float* W1 = (const float*)d_in[4];
  const float* b1 = (const float*)d_in[5];
  const float* W2 = (const float*)d_in[6];
  const float* b2 = (const float*)d_in[7];
  const float* W3 = (const float*)d_in[8];
  const float* b3 = (const float*)d_in[9];
  float* out = (float*)d_out;

  const int N = in_sizes[0] / 256;  // 50000 < 65536: packed records valid
  const int E = in_sizes[1] / 2;
  const int* src = ei;
  const int* dst = ei + E;
  const int NB = (N + 255) >> 8;

  char* ws = (char*)d_ws;
  auto alloc = [&](size_t bytes) -> char* {
    char* p = ws;
    ws += (bytes + 255) & ~(size_t)255;
    return p;
  };
  int* bcnt = (int*)alloc(256 * 4);
  int* bbase = (int*)alloc(257 * 4);
  int* bcur = (int*)alloc(256 * 4);
  unsigned int* binned = (unsigned int*)alloc((size_t)E * 4);
  int* srcs = (int*)alloc((size_t)E * 4);
  int* offs = (int*)alloc((size_t)(N + 1) * 4);
  float* dinv = (float*)alloc((size_t)N * 4);
  int2* edges = (int2*)alloc((size_t)E * 8);
  float* mu = (float*)alloc((size_t)N * 4);
  float* rs = (float*)alloc((size_t)N * 4);
  half_t* t = (half_t*)alloc((size_t)N * 128 * 2);
  half_t* h = (half_t*)alloc((size_t)N * 128 * 2);
  unsigned short* W1t_hi = (unsigned short*)alloc(256 * 128 * 2);
  unsigned short* W1t_lo = (unsigned short*)alloc(256 * 128 * 2);
  unsigned short* W2t_hi = (unsigned short*)alloc(128 * 128 * 2);
  unsigned short* W2t_lo = (unsigned short*)alloc(128 * 128 * 2);
  unsigned short* W3t_hi = (unsigned short*)alloc(128 * 64 * 2);
  unsigned short* W3t_lo = (unsigned short*)alloc(128 * 64 * 2);

  // ---- prep: zero ctl + wsplit x3 + ln_stats in one launch ----
  const int ln_blocks = (N + 3) / 4;
  prep_misc<<<225 + ln_blocks, 256, 0, stream>>>(
      x, W1, W2, W3, bcnt, bcur, W1t_hi, W1t_lo, W2t_hi, W2t_lo, W3t_hi, W3t_lo,
      mu, rs, N);

  // ---- CSR build via 2-level bucket sort (packed records) ----
  hist_bucket<<<256, 256, 0, stream>>>(dst, bcnt, E, NB);
  scan_buckets<<<1, 256, 0, stream>>>(bcnt, bbase, bcur, NB, E);
  scatter_bins<<<(E + CHUNK - 1) / CHUNK, 256, 0, stream>>>(src, dst, bcur, binned, E);
  sort_bucket<<<NB, 256, 0, stream>>>(binned, bbase, srcs, offs, dinv, N, NB, E);
  fill_w<<<(E + 255) / 256, 256, 0, stream>>>(srcs, dinv, edges, E);

  const int gemm_blocks = (N + 63) / 64;
  const int agg_blocks = (N + 3) / 4;

  // ---- layer 1 ----
  gemm_mfma<256, 128, true, false><<<gemm_blocks, 256, 0, stream>>>(
      x, W1t_hi, W1t_lo, mu, rs, gamma, beta, t, N);
  agg128_h<<<agg_blocks, 256, 0, stream>>>(t, offs, edges, dinv, b1, h, N);

  // ---- layer 2 ----
  gemm_mfma<128, 128, false, true><<<gemm_blocks, 256, 0, stream>>>(
      h, W2t_hi, W2t_lo, nullptr, nullptr, nullptr, nullptr, t, N);
  agg128_h<<<agg_blocks, 256, 0, stream>>>(t, offs, edges, dinv, b2, h, N);

  // ---- layer 3 ----
  gemm_mfma<128, 64, false, true><<<gemm_blocks, 256, 0, stream>>>(
      h, W3t_hi, W3t_lo, nullptr, nullptr, nullptr, nullptr, t, N);
  agg64_h<<<agg_blocks, 256, 0, stream>>>(t, offs, edges, dinv, b3, out, N);
}

// Round 11
// 290.004 us; speedup vs baseline: 1.0963x; 1.0963x over previous
//
#include <hip/hip_runtime.h>
#include <cstdint>
#include <cstddef>

// ---------------------------------------------------------------------------
// GCN encoder: z = GCN3( relu(GCN2( relu(GCN1( LN(x) )) )) )
// R11: R9 GEMM restored exactly (R10's register-dbuf spilled to scratch:
//      WRITE_SIZE 53 MB vs 12.5 MB output -> 2x slower). Packed 4B CSR
//      records kept from R10 (neutral-to-positive). Agg kernels: R7 form.
// ---------------------------------------------------------------------------

typedef __attribute__((ext_vector_type(8))) __bf16 bf16x8;
typedef __attribute__((ext_vector_type(4))) float f32x4;
typedef _Float16 half_t;
typedef __attribute__((ext_vector_type(8))) _Float16 half8_t;

// ---------------- prep: zero ctl | wsplit x3 | ln_stats, by block range ----
__global__ __launch_bounds__(256) void prep_misc(
    const float* __restrict__ x, const float* __restrict__ W1,
    const float* __restrict__ W2, const float* __restrict__ W3,
    int* __restrict__ bcnt, int* __restrict__ bcur_zero,
    unsigned short* __restrict__ W1t_hi, unsigned short* __restrict__ W1t_lo,
    unsigned short* __restrict__ W2t_hi, unsigned short* __restrict__ W2t_lo,
    unsigned short* __restrict__ W3t_hi, unsigned short* __restrict__ W3t_lo,
    float* __restrict__ mu, float* __restrict__ rs, int n) {
  int blk = blockIdx.x;
  int tid = threadIdx.x;
  if (blk == 0) {
    bcnt[tid] = 0;
    bcur_zero[tid] = 0;
    return;
  }
  if (blk <= 224) {
    int idx = (blk - 1) * 256 + tid;
    const float* W;
    unsigned short *Th, *Tl;
    int K, NOUT;
    if (idx < 32768) {
      W = W1; Th = W1t_hi; Tl = W1t_lo; K = 256; NOUT = 128;
    } else if (idx < 49152) {
      idx -= 32768;
      W = W2; Th = W2t_hi; Tl = W2t_lo; K = 128; NOUT = 128;
    } else {
      idx -= 49152;
      W = W3; Th = W3t_hi; Tl = W3t_lo; K = 128; NOUT = 64;
    }
    int k = idx / NOUT, c = idx % NOUT;
    float v = W[idx];
    __bf16 h = (__bf16)v;
    __bf16 l = (__bf16)(v - (float)h);
    Th[(size_t)c * K + k] = __builtin_bit_cast(unsigned short, h);
    Tl[(size_t)c * K + k] = __builtin_bit_cast(unsigned short, l);
    return;
  }
  int wv = (blk - 225) * 4 + (tid >> 6);
  int lane = tid & 63;
  if (wv >= n) return;
  const float4* row = (const float4*)(x + (size_t)wv * 256);
  float4 v = row[lane];
  float s = v.x + v.y + v.z + v.w;
  float s2 = v.x * v.x + v.y * v.y + v.z * v.z + v.w * v.w;
  for (int off = 32; off > 0; off >>= 1) {
    s += __shfl_down(s, off);
    s2 += __shfl_down(s2, off);
  }
  if (lane == 0) {
    float m = s * (1.0f / 256.0f);
    float var = s2 * (1.0f / 256.0f) - m * m;
    mu[wv] = m;
    rs[wv] = rsqrtf(var + 1e-5f);
  }
}

// ---------------- CSR build: bucket sort by dst (packed 4B records) --------
__global__ __launch_bounds__(256) void hist_bucket(const int* __restrict__ dst,
                                                   int* __restrict__ bcnt, int E, int NB) {
  __shared__ int h[256];
  int t = threadIdx.x;
  h[t] = 0;
  __syncthreads();
  for (int e = blockIdx.x * 256 + t; e < E; e += gridDim.x * 256)
    atomicAdd(&h[dst[e] >> 8], 1);
  __syncthreads();
  if (t < NB && h[t]) atomicAdd(&bcnt[t], h[t]);
}

__global__ __launch_bounds__(256) void scan_buckets(const int* __restrict__ bcnt,
                                                    int* __restrict__ bbase,
                                                    int* __restrict__ bcur, int NB, int E) {
  __shared__ int tmp[256];
  int t = threadIdx.x;
  int v = (t < NB) ? bcnt[t] : 0;
  tmp[t] = v;
  __syncthreads();
  for (int off = 1; off < 256; off <<= 1) {
    int x = (t >= off) ? tmp[t - off] : 0;
    __syncthreads();
    tmp[t] += x;
    __syncthreads();
  }
  int excl = tmp[t] - v;
  if (t < NB) { bbase[t] = excl; bcur[t] = excl; }
  if (t == 0) bbase[NB] = E;
}

#define CHUNK 4096
// record = (dst << 16) | src  (both < 65536)
__global__ __launch_bounds__(256) void scatter_bins(const int* __restrict__ src,
                                                    const int* __restrict__ dst,
                                                    int* __restrict__ bcur,
                                                    unsigned int* __restrict__ binned, int E) {
  __shared__ unsigned int recs[CHUNK];  // 16 KB
  __shared__ int hist[256], lbase[256], resv[256], cur[256];
  int t = threadIdx.x;
  int e0 = blockIdx.x * CHUNK;
  if (e0 >= E) return;
  int len = min(CHUNK, E - e0);
  hist[t] = 0;
  cur[t] = 0;
  __syncthreads();
  for (int i = t; i < len; i += 256) atomicAdd(&hist[dst[e0 + i] >> 8], 1);
  __syncthreads();
  int v = hist[t];
  lbase[t] = v;
  __syncthreads();
  for (int off = 1; off < 256; off <<= 1) {
    int x = (t >= off) ? lbase[t - off] : 0;
    __syncthreads();
    lbase[t] += x;
    __syncthreads();
  }
  int myexcl = lbase[t] - v;
  if (v) resv[t] = atomicAdd(&bcur[t], v);
  __syncthreads();
  lbase[t] = myexcl;
  __syncthreads();
  for (int i = t; i < len; i += 256) {
    int d = dst[e0 + i], s = src[e0 + i];
    int b = d >> 8;
    int r = atomicAdd(&cur[b], 1);
    recs[lbase[b] + r] = ((unsigned int)d << 16) | (unsigned int)s;
  }
  __syncthreads();
  for (int i = t; i < len; i += 256) {
    unsigned int rc = recs[i];
    int b = rc >> 24;
    binned[resv[b] + (i - lbase[b])] = rc;
  }
}

#define MAXB 8192
// counting-sort one 256-node bucket; binned re-read from L2 (no record LDS)
__global__ __launch_bounds__(256) void sort_bucket(const unsigned int* __restrict__ binned,
                                                   const int* __restrict__ bbase,
                                                   int* __restrict__ srcs,
                                                   int* __restrict__ offs,
                                                   float* __restrict__ dinv,
                                                   int N, int NB, int E) {
  __shared__ int sstage[MAXB];  // 32 KB
  __shared__ int hist[256], nbase[256], cur[256], tmp[256];
  int b = blockIdx.x, t = threadIdx.x;
  int base = bbase[b], end = bbase[b + 1];
  int L = end - base;
  if (L > MAXB) L = MAXB;
  hist[t] = 0;
  __syncthreads();
  for (int i = t; i < L; i += 256)
    atomicAdd(&hist[(binned[base + i] >> 16) & 255], 1);
  __syncthreads();
  int v = hist[t];
  tmp[t] = v;
  __syncthreads();
  for (int off = 1; off < 256; off <<= 1) {
    int x = (t >= off) ? tmp[t - off] : 0;
    __syncthreads();
    tmp[t] += x;
    __syncthreads();
  }
  int excl = tmp[t] - v;
  nbase[t] = excl;
  cur[t] = excl;
  int node = (b << 8) + t;
  if (node < N) {
    offs[node] = base + excl;
    dinv[node] = rsqrtf(1.0f + (float)v);
  }
  if (b == NB - 1 && t == 0) offs[N] = E;
  __syncthreads();
  for (int i = t; i < L; i += 256) {
    unsigned int p = binned[base + i];
    int ld = (p >> 16) & 255;
    int slot = atomicAdd(&cur[ld], 1);
    sstage[slot] = (int)(p & 0xFFFFu);
  }
  __syncthreads();
  for (int i = t; i < L; i += 256) srcs[base + i] = sstage[i];
}

__global__ void fill_w(const int* __restrict__ srcs, const float* __restrict__ dinv,
                       int2* __restrict__ edges, int E) {
  int e = blockIdx.x * 256 + threadIdx.x;
  if (e < E) {
    int s = srcs[e];
    edges[e] = make_int2(s, __float_as_int(dinv[s]));
  }
}

// ---------------- single-buffer bf16x3 MFMA GEMM (R9 form) ----------------
template <int K, int NOUT, bool LN, bool A_FP16>
__launch_bounds__(256)
__global__ void gemm_mfma(const void* __restrict__ Avoid,
                          const unsigned short* __restrict__ Wt_hi,
                          const unsigned short* __restrict__ Wt_lo,
                          const float* __restrict__ mu, const float* __restrict__ rs,
                          const float* __restrict__ gamma, const float* __restrict__ beta,
                          half_t* __restrict__ out, int nrows) {
  constexpr int BM = 64, BK = 32;
  constexpr int NT = NOUT / 16;
  __shared__ unsigned short As_hi[BM][BK];
  __shared__ unsigned short As_lo[BM][BK];
  __shared__ unsigned short Bs_hi[NOUT][BK];
  __shared__ unsigned short Bs_lo[NOUT][BK];

  const int tid = threadIdx.x;
  const int lane = tid & 63;
  const int w = tid >> 6;
  const int quad = lane >> 4;
  const int l16 = lane & 15;
  const int row0 = blockIdx.x * BM;

  f32x4 acc[NT];
#pragma unroll
  for (int t = 0; t < NT; ++t) acc[t] = (f32x4){0.f, 0.f, 0.f, 0.f};

  for (int k0 = 0; k0 < K; k0 += BK) {
    if (!A_FP16) {
      const float* A = (const float*)Avoid;
#pragma unroll
      for (int i = 0; i < 2; ++i) {
        int r = i * 32 + (tid >> 3);
        int c4 = (tid & 7) * 4;
        int grow = row0 + r;
        if (grow > nrows - 1) grow = nrows - 1;
        float4 v = *(const float4*)&A[(size_t)grow * K + k0 + c4];
        if (LN) {
          float m = mu[grow], s = rs[grow];
          float4 g = *(const float4*)&gamma[k0 + c4];
          float4 b = *(const float4*)&beta[k0 + c4];
          v.x = (v.x - m) * s * g.x + b.x;
          v.y = (v.y - m) * s * g.y + b.y;
          v.z = (v.z - m) * s * g.z + b.z;
          v.w = (v.w - m) * s * g.w + b.w;
        }
        float vv[4] = {v.x, v.y, v.z, v.w};
#pragma unroll
        for (int j = 0; j < 4; ++j) {
          __bf16 h = (__bf16)vv[j];
          __bf16 l = (__bf16)(vv[j] - (float)h);
          As_hi[r][c4 + j] = __builtin_bit_cast(unsigned short, h);
          As_lo[r][c4 + j] = __builtin_bit_cast(unsigned short, l);
        }
      }
    } else {
      const half_t* A = (const half_t*)Avoid;
      int r = tid >> 2;
      int c8 = (tid & 3) * 8;
      int grow = row0 + r;
      if (grow > nrows - 1) grow = nrows - 1;
      half8_t v = *(const half8_t*)&A[(size_t)grow * K + k0 + c8];
#pragma unroll
      for (int j = 0; j < 8; ++j) {
        float f = (float)v[j];
        __bf16 h = (__bf16)f;
        __bf16 l = (__bf16)(f - (float)h);
        As_hi[r][c8 + j] = __builtin_bit_cast(unsigned short, h);
        As_lo[r][c8 + j] = __builtin_bit_cast(unsigned short, l);
      }
    }
#pragma unroll
    for (int i = 0; i < NOUT / 64; ++i) {
      int n = i * 64 + (tid >> 2);
      int c8 = (tid & 3) * 8;
      *(uint4*)&Bs_hi[n][c8] = *(const uint4*)&Wt_hi[(size_t)n * K + k0 + c8];
      *(uint4*)&Bs_lo[n][c8] = *(const uint4*)&Wt_lo[(size_t)n * K + k0 + c8];
    }
    __syncthreads();

    bf16x8 ah = *(const bf16x8*)&As_hi[w * 16 + l16][quad * 8];
    bf16x8 al = *(const bf16x8*)&As_lo[w * 16 + l16][quad * 8];
#pragma unroll
    for (int t = 0; t < NT; ++t) {
      bf16x8 bh = *(const bf16x8*)&Bs_hi[t * 16 + l16][quad * 8];
      bf16x8 bl = *(const bf16x8*)&Bs_lo[t * 16 + l16][quad * 8];
      acc[t] = __builtin_amdgcn_mfma_f32_16x16x32_bf16(ah, bh, acc[t], 0, 0, 0);
      acc[t] = __builtin_amdgcn_mfma_f32_16x16x32_bf16(al, bh, acc[t], 0, 0, 0);
      acc[t] = __builtin_amdgcn_mfma_f32_16x16x32_bf16(ah, bl, acc[t], 0, 0, 0);
    }
    __syncthreads();
  }

#pragma unroll
  for (int t = 0; t < NT; ++t) {
#pragma unroll
    for (int r = 0; r < 4; ++r) {
      int grow = row0 + w * 16 + quad * 4 + r;
      if (grow < nrows) out[(size_t)grow * NOUT + t * 16 + l16] = (half_t)acc[t][r];
    }
  }
}

// ---------------- aggregation: quarter-wave gathers (R7) ----------------
__global__ __launch_bounds__(256) void agg128_h(const half_t* __restrict__ t,
                                                const int* __restrict__ offs,
                                                const int2* __restrict__ edges,
                                                const float* __restrict__ dinv,
                                                const float* __restrict__ bias,
                                                half_t* __restrict__ out, int n) {
  int gid = blockIdx.x * blockDim.x + threadIdx.x;
  int node = gid >> 6, lane = gid & 63;
  if (node >= n) return;
  int qw = lane >> 4;
  int fl = lane & 15;
  int e0 = offs[node], e1 = offs[node + 1];
  float acc[8] = {0.f, 0.f, 0.f, 0.f, 0.f, 0.f, 0.f, 0.f};
  int e = e0 + qw;
  for (; e + 12 < e1; e += 16) {
    int2 da = edges[e], db = edges[e + 4], dc = edges[e + 8], dd = edges[e + 12];
    half8_t va = *(const half8_t*)(t + ((size_t)da.x << 7) + fl * 8);
    half8_t vb = *(const half8_t*)(t + ((size_t)db.x << 7) + fl * 8);
    half8_t vc = *(const half8_t*)(t + ((size_t)dc.x << 7) + fl * 8);
    half8_t vd = *(const half8_t*)(t + ((size_t)dd.x << 7) + fl * 8);
    float wa = __int_as_float(da.y), wb = __int_as_float(db.y);
    float wc = __int_as_float(dc.y), wd = __int_as_float(dd.y);
#pragma unroll
    for (int j = 0; j < 8; ++j) {
      acc[j] = fmaf(wa, (float)va[j], acc[j]);
      acc[j] = fmaf(wb, (float)vb[j], acc[j]);
      acc[j] = fmaf(wc, (float)vc[j], acc[j]);
      acc[j] = fmaf(wd, (float)vd[j], acc[j]);
    }
  }
  for (; e < e1; e += 4) {
    int2 d = edges[e];
    half8_t v = *(const half8_t*)(t + ((size_t)d.x << 7) + fl * 8);
    float w = __int_as_float(d.y);
#pragma unroll
    for (int j = 0; j < 8; ++j) acc[j] = fmaf(w, (float)v[j], acc[j]);
  }
#pragma unroll
  for (int j = 0; j < 8; ++j) {
    acc[j] += __shfl_xor(acc[j], 16);
    acc[j] += __shfl_xor(acc[j], 32);
  }
  if (qw == 0) {
    float di = dinv[node];
    float dii = di * di;
    half8_t sv = *(const half8_t*)(t + ((size_t)node << 7) + fl * 8);
    float4 b0 = *(const float4*)(bias + fl * 8);
    float4 b1 = *(const float4*)(bias + fl * 8 + 4);
    float bb[8] = {b0.x, b0.y, b0.z, b0.w, b1.x, b1.y, b1.z, b1.w};
    half8_t o;
#pragma unroll
    for (int j = 0; j < 8; ++j) {
      float v = di * acc[j] + dii * (float)sv[j] + bb[j];
      o[j] = (half_t)fmaxf(v, 0.f);
    }
    *(half8_t*)(out + ((size_t)node << 7) + fl * 8) = o;
  }
}

__global__ __launch_bounds__(256) void agg64_h(const half_t* __restrict__ t,
                                               const int* __restrict__ offs,
                                               const int2* __restrict__ edges,
                                               const float* __restrict__ dinv,
                                               const float* __restrict__ bias,
                                               float* __restrict__ out, int n) {
  int gid = blockIdx.x * blockDim.x + threadIdx.x;
  int node = gid >> 6, lane = gid & 63;
  if (node >= n) return;
  int og = lane >> 3;
  int fl = lane & 7;
  int e0 = offs[node], e1 = offs[node + 1];
  float acc[8] = {0.f, 0.f, 0.f, 0.f, 0.f, 0.f, 0.f, 0.f};
  int e = e0 + og;
  for (; e + 8 < e1; e += 16) {
    int2 da = edges[e], db = edges[e + 8];
    half8_t va = *(const half8_t*)(t + ((size_t)da.x << 6) + fl * 8);
    half8_t vb = *(const half8_t*)(t + ((size_t)db.x << 6) + fl * 8);
    float wa = __int_as_float(da.y), wb = __int_as_float(db.y);
#pragma unroll
    for (int j = 0; j < 8; ++j) {
      acc[j] = fmaf(wa, (float)va[j], acc[j]);
      acc[j] = fmaf(wb, (float)vb[j], acc[j]);
    }
  }
  for (; e < e1; e += 8) {
    int2 d = edges[e];
    half8_t v = *(const half8_t*)(t + ((size_t)d.x << 6) + fl * 8);
    float w = __int_as_float(d.y);
#pragma unroll
    for (int j = 0; j < 8; ++j) acc[j] = fmaf(w, (float)v[j], acc[j]);
  }
#pragma unroll
  for (int j = 0; j < 8; ++j) {
    acc[j] += __shfl_xor(acc[j], 8);
    acc[j] += __shfl_xor(acc[j], 16);
    acc[j] += __shfl_xor(acc[j], 32);
  }
  if (og == 0) {
    float di = dinv[node];
    float dii = di * di;
    half8_t sv = *(const half8_t*)(t + ((size_t)node << 6) + fl * 8);
    float4 b0 = *(const float4*)(bias + fl * 8);
    float4 b1 = *(const float4*)(bias + fl * 8 + 4);
    float bb[8] = {b0.x, b0.y, b0.z, b0.w, b1.x, b1.y, b1.z, b1.w};
    float ov[8];
#pragma unroll
    for (int j = 0; j < 8; ++j) ov[j] = di * acc[j] + dii * (float)sv[j] + bb[j];
    *(float4*)(out + ((size_t)node << 6) + fl * 8) = make_float4(ov[0], ov[1], ov[2], ov[3]);
    *(float4*)(out + ((size_t)node << 6) + fl * 8 + 4) = make_float4(ov[4], ov[5], ov[6], ov[7]);
  }
}

extern "C" void kernel_launch(void* const* d_in, const int* in_sizes, int n_in,
                              void* d_out, int out_size, void* d_ws, size_t ws_size,
                              hipStream_t stream) {
  const float* x = (const float*)d_in[0];
  const int* ei = (const int*)d_in[1];
  const float* gamma = (const float*)d_in[2];
  const float* beta = (const float*)d_in[3];
  const float* W1 = (const float*)d_in[4];
  const float* b1 = (const float*)d_in[5];
  const float* W2 = (const float*)d_in[6];
  const float* b2 = (const float*)d_in[7];
  const float* W3 = (const float*)d_in[8];
  const float* b3 = (const float*)d_in[9];
  float* out = (float*)d_out;

  const int N = in_sizes[0] / 256;  // 50000 < 65536: packed records valid
  const int E = in_sizes[1] / 2;
  const int* src = ei;
  const int* dst = ei + E;
  const int NB = (N + 255) >> 8;

  char* ws = (char*)d_ws;
  auto alloc = [&](size_t bytes) -> char* {
    char* p = ws;
    ws += (bytes + 255) & ~(size_t)255;
    return p;
  };
  int* bcnt = (int*)alloc(256 * 4);
  int* bbase = (int*)alloc(257 * 4);
  int* bcur = (int*)alloc(256 * 4);
  unsigned int* binned = (unsigned int*)alloc((size_t)E * 4);
  int* srcs = (int*)alloc((size_t)E * 4);
  int* offs = (int*)alloc((size_t)(N + 1) * 4);
  float* dinv = (float*)alloc((size_t)N * 4);
  int2* edges = (int2*)alloc((size_t)E * 8);
  float* mu = (float*)alloc((size_t)N * 4);
  float* rs = (float*)alloc((size_t)N * 4);
  half_t* t = (half_t*)alloc((size_t)N * 128 * 2);
  half_t* h = (half_t*)alloc((size_t)N * 128 * 2);
  unsigned short* W1t_hi = (unsigned short*)alloc(256 * 128 * 2);
  unsigned short* W1t_lo = (unsigned short*)alloc(256 * 128 * 2);
  unsigned short* W2t_hi = (unsigned short*)alloc(128 * 128 * 2);
  unsigned short* W2t_lo = (unsigned short*)alloc(128 * 128 * 2);
  unsigned short* W3t_hi = (unsigned short*)alloc(128 * 64 * 2);
  unsigned short* W3t_lo = (unsigned short*)alloc(128 * 64 * 2);

  // ---- prep: zero ctl + wsplit x3 + ln_stats in one launch ----
  const int ln_blocks = (N + 3) / 4;
  prep_misc<<<225 + ln_blocks, 256, 0, stream>>>(
      x, W1, W2, W3, bcnt, bcur, W1t_hi, W1t_lo, W2t_hi, W2t_lo, W3t_hi, W3t_lo,
      mu, rs, N);

  // ---- CSR build via 2-level bucket sort (packed records) ----
  hist_bucket<<<256, 256, 0, stream>>>(dst, bcnt, E, NB);
  scan_buckets<<<1, 256, 0, stream>>>(bcnt, bbase, bcur, NB, E);
  scatter_bins<<<(E + CHUNK - 1) / CHUNK, 256, 0, stream>>>(src, dst, bcur, binned, E);
  sort_bucket<<<NB, 256, 0, stream>>>(binned, bbase, srcs, offs, dinv, N, NB, E);
  fill_w<<<(E + 255) / 256, 256, 0, stream>>>(srcs, dinv, edges, E);

  const int gemm_blocks = (N + 63) / 64;
  const int agg_blocks = (N + 3) / 4;

  // ---- layer 1 ----
  gemm_mfma<256, 128, true, false><<<gemm_blocks, 256, 0, stream>>>(
      x, W1t_hi, W1t_lo, mu, rs, gamma, beta, t, N);
  agg128_h<<<agg_blocks, 256, 0, stream>>>(t, offs, edges, dinv, b1, h, N);

  // ---- layer 2 ----
  gemm_mfma<128, 128, false, true><<<gemm_blocks, 256, 0, stream>>>(
      h, W2t_hi, W2t_lo, nullptr, nullptr, nullptr, nullptr, t, N);
  agg128_h<<<agg_blocks, 256, 0, stream>>>(t, offs, edges, dinv, b2, h, N);

  // ---- layer 3 ----
  gemm_mfma<128, 64, false, true><<<gemm_blocks, 256, 0, stream>>>(
      h, W3t_hi, W3t_lo, nullptr, nullptr, nullptr, nullptr, t, N);
  agg64_h<<<agg_blocks, 256, 0, stream>>>(t, offs, edges, dinv, b3, out, N);
}